// Round 2
// baseline (452.580 us; speedup 1.0000x reference)
//
#include <hip/hip_runtime.h>

typedef __bf16 bf16;
typedef __bf16 bf16x4 __attribute__((ext_vector_type(4)));
typedef __bf16 bf16x8 __attribute__((ext_vector_type(8)));
typedef float  f32x4  __attribute__((ext_vector_type(4)));
typedef int    int4v  __attribute__((ext_vector_type(4)));

#define NTOK 4096
#define NH   12
#define HD   64
#define CDIM 768

// C^-0.5 * log2(e), folded into Q at projection time
#define K2SCALE 0.05205928442089389f

// XOR-swizzled LDS addressing: rows are 64 bf16 = 128 B = 8 x 16B blocks.
// block' = block ^ (row & 7). Verified conflict-free (uniform bank spread)
// for: b128 staging writes, b128 fragment reads, b64 P writes.
__device__ __forceinline__ bf16* swz(bf16* base, int row, int byteoff) {
  return (bf16*)((char*)base + row * 128 +
                 ((((byteoff >> 4) ^ (row & 7)) << 4) | (byteoff & 15)));
}
__device__ __forceinline__ const bf16* swz(const bf16* base, int row, int byteoff) {
  return (const bf16*)((const char*)base + row * 128 +
                 ((((byteoff >> 4) ^ (row & 7)) << 4) | (byteoff & 15)));
}

// ---------------------------------------------------------------------------
// 1) fp32 -> bf16 cast for x, Wq, Wk
// ---------------------------------------------------------------------------
__global__ __launch_bounds__(256) void cast_kernel(
    const float* __restrict__ x, const float* __restrict__ wq, const float* __restrict__ wk,
    bf16* __restrict__ xb, bf16* __restrict__ wqb, bf16* __restrict__ wkb,
    long nx, long nw) {
  long i4 = ((long)blockIdx.x * 256 + threadIdx.x) * 4;
  if (i4 >= nx + 2 * nw) return;
  const float* src; bf16* dst;
  if (i4 < nx)            { src = x  + i4;            dst = xb  + i4; }
  else if (i4 < nx + nw)  { src = wq + (i4 - nx);     dst = wqb + (i4 - nx); }
  else                    { src = wk + (i4 - nx - nw); dst = wkb + (i4 - nx - nw); }
  f32x4 v = *(const f32x4*)src;
  *(bf16x4*)dst = __builtin_convertvector(v, bf16x4);
}

// ---------------------------------------------------------------------------
// 2) projection GEMM (round-0 known-good): y = x @ W^T, tile 128x128, BK=64,
//    reg-prefetch staging, swizzled LDS. blockIdx.z: 0->Q(scaled), 1->K.
//    out layout [B, H, N, 64]
// ---------------------------------------------------------------------------
__global__ __launch_bounds__(256) void proj_kernel(
    const bf16* __restrict__ xb, const bf16* __restrict__ wqb, const bf16* __restrict__ wkb,
    bf16* __restrict__ Qb, bf16* __restrict__ Kb) {
  __shared__ __align__(16) bf16 Ap[128 * 64];
  __shared__ __align__(16) bf16 Bp[128 * 64];
  const int tid = threadIdx.x;
  const int w = tid >> 6, lane = tid & 63, l15 = lane & 15, quad = lane >> 4;
  const int m0 = blockIdx.x * 128;
  const int j0 = blockIdx.y * 128;
  const bf16* W   = blockIdx.z ? wkb : wqb;
  bf16*       Out = blockIdx.z ? Kb  : Qb;
  const float oscale = blockIdx.z ? 1.0f : K2SCALE;

  // per-thread staging geometry: rows (tid>>3)+i*32, 16B chunk (tid&7)
  const int srow = tid >> 3, scb = (tid & 7) * 16, soff = (tid & 7) * 8;
  const bf16* pa = xb + (long)(m0 + srow) * CDIM + soff;
  const bf16* pb = W  + (long)(j0 + srow) * CDIM + soff;

  f32x4 acc[2][8] = {};
  int4v rA[4], rB[4];
#pragma unroll
  for (int i = 0; i < 4; ++i) {
    rA[i] = *(const int4v*)(pa + (long)i * 32 * CDIM);
    rB[i] = *(const int4v*)(pb + (long)i * 32 * CDIM);
  }

  for (int kt = 0; kt < CDIM / 64; ++kt) {
    __syncthreads();  // previous tile's LDS reads done
#pragma unroll
    for (int i = 0; i < 4; ++i) {
      *(int4v*)swz(Ap, srow + i * 32, scb) = rA[i];
      *(int4v*)swz(Bp, srow + i * 32, scb) = rB[i];
    }
    __syncthreads();
    // prefetch next K-slice while computing this one
    const long koff = (long)((kt == CDIM / 64 - 1) ? kt : kt + 1) * 64;
#pragma unroll
    for (int i = 0; i < 4; ++i) {
      rA[i] = *(const int4v*)(pa + (long)i * 32 * CDIM + koff);
      rB[i] = *(const int4v*)(pb + (long)i * 32 * CDIM + koff);
    }
#pragma unroll
    for (int kk = 0; kk < 2; ++kk) {
      bf16x8 a[2], b[8];
#pragma unroll
      for (int rt = 0; rt < 2; ++rt)
        a[rt] = *(const bf16x8*)swz(Ap, w * 32 + rt * 16 + l15, kk * 64 + quad * 16);
#pragma unroll
      for (int ct = 0; ct < 8; ++ct)
        b[ct] = *(const bf16x8*)swz(Bp, ct * 16 + l15, kk * 64 + quad * 16);
#pragma unroll
      for (int rt = 0; rt < 2; ++rt)
#pragma unroll
        for (int ct = 0; ct < 8; ++ct)
          acc[rt][ct] = __builtin_amdgcn_mfma_f32_16x16x32_bf16(a[rt], b[ct], acc[rt][ct], 0, 0, 0);
    }
  }
#pragma unroll
  for (int rt = 0; rt < 2; ++rt)
#pragma unroll
    for (int ct = 0; ct < 8; ++ct)
#pragma unroll
      for (int reg = 0; reg < 4; ++reg) {
        int m = m0 + w * 32 + rt * 16 + quad * 4 + reg;
        int j = j0 + ct * 16 + l15;
        int b = m >> 12, n = m & (NTOK - 1);
        int h = j >> 6, d = j & (HD - 1);
        Out[(((long)(b * NH + h) * NTOK + n) << 6) + d] = (bf16)(acc[rt][ct][reg] * oscale);
      }
}

// ---------------------------------------------------------------------------
// 3) K [B,H,N,64] -> Kt [B,H,64,N]
// ---------------------------------------------------------------------------
__global__ __launch_bounds__(256) void transpose_kernel(
    const bf16* __restrict__ Kb, bf16* __restrict__ Ktb) {
  __shared__ __align__(16) bf16 T[64 * 72];
  const int tid = threadIdx.x;
  const int n0 = blockIdx.x * 64;
  const long bh = blockIdx.y;
#pragma unroll
  for (int i = 0; i < 2; ++i) {
    int c = tid + i * 256;
    int row = c >> 3, off = (c & 7) * 8;
    bf16x8 v = *(const bf16x8*)(Kb + ((bh << 12) + n0 + row) * HD + off);
#pragma unroll
    for (int e = 0; e < 8; ++e) T[(off + e) * 72 + row] = v[e];
  }
  __syncthreads();
#pragma unroll
  for (int i = 0; i < 2; ++i) {
    int c = tid + i * 256;
    int d = c >> 3, koff = (c & 7) * 8;
    int4v v = *(const int4v*)(&T[d * 72 + koff]);
    *(int4v*)(Ktb + ((bh << 6) + d) * (long)NTOK + n0 + koff) = v;
  }
}

// ---------------------------------------------------------------------------
// 4) flash attention, transposed orientation, BARRIER-FREE main loop:
//      S^T = K · Q^T ; P = exp2(S) (no max; scale folded into Q)
//      O^T = V^T · P^T  (V == K, reference bug preserved)
//    K/Kt fragments are loaded DIRECTLY from global (L1/L2-resident; all 4
//    waves read identical tiles, per-head working set ~1MB << 4MB XCD L2).
//    LDS holds only Q (staged once) then wave-private P rows -> after the
//    single post-Q-staging barrier, the main loop has ZERO __syncthreads.
// ---------------------------------------------------------------------------
__global__ __launch_bounds__(256, 3) void attn_kernel(
    const bf16* __restrict__ Qb, const bf16* __restrict__ Kb, const bf16* __restrict__ Ktb,
    float* __restrict__ out) {
  __shared__ __align__(16) bf16 QP[128 * 64];  // Q tile, then P [qrow][key]

  const int tid = threadIdx.x;
  const int w = tid >> 6, lane = tid & 63, l15 = lane & 15, quad = lane >> 4;
  const int q0 = blockIdx.x * 128;
  const int bh = blockIdx.y;
  const int b = bh / NH, h = bh % NH;
  const bf16* Qhead  = Qb  + (long)bh * NTOK * HD;
  const bf16* Khead  = Kb  + (long)bh * NTOK * HD;
  const bf16* Kthead = Ktb + (long)bh * HD * NTOK;

  // stage Q tile (128 x 64) via regs + swizzled ds_write
#pragma unroll
  for (int i = 0; i < 4; ++i) {
    int c = tid + i * 256;
    int row = c >> 3, cb = (c & 7) * 16;
    int4v v = *(const int4v*)(Qhead + (long)(q0 + row) * HD + (c & 7) * 8);
    *(int4v*)swz(QP, row, cb) = v;
  }
  __syncthreads();  // the ONLY barrier: Q resident for all waves

  // Q^T B-frags: B[k=d][n=qrow], lane l15 = qrow, k = quad*8+j (+32*kk)
  bf16x8 bq[2][2];
#pragma unroll
  for (int nt = 0; nt < 2; ++nt)
#pragma unroll
    for (int kk = 0; kk < 2; ++kk)
      bq[nt][kk] = *(const bf16x8*)swz(QP, w * 32 + nt * 16 + l15, kk * 64 + quad * 16);
  // From here on, QP rows [w*32, w*32+32) are wave-private P space.

  // per-lane global fragment bases:
  //   ak[mt][kk] = K [kt*64 + mt*16 + l15][kk*32 + quad*8 ..+8]
  //   av[mt][kk] = Kt[mt*16 + l15][kt*64 + kk*32 + quad*8 ..+8]
  const bf16* pK  = Khead  + l15 * HD + quad * 8;
  const bf16* pKt = Kthead + (long)l15 * NTOK + quad * 8;

  f32x4 o[4][2] = {};          // O^T: mt over d (4), nt over qrow (2)
  float lacc[2] = {0.f, 0.f};  // per-lane partial softmax denominators

  for (int kt = 0; kt < NTOK / 64; ++kt) {
    const bf16* tK  = pK  + (long)kt * 64 * HD;
    const bf16* tKt = pKt + (long)kt * 64;

    // K fragments straight from global (L1/L2)
    bf16x8 ak[4][2];
#pragma unroll
    for (int mt = 0; mt < 4; ++mt)
#pragma unroll
      for (int kk = 0; kk < 2; ++kk)
        ak[mt][kk] = *(const bf16x8*)(tK + mt * 16 * HD + kk * 32);

    // S^T = K Q^T : s[mt][nt], rows (quad*4+reg) = keys, col (l15) = qrow
    f32x4 s[4][2] = {};
    __builtin_amdgcn_s_setprio(1);
#pragma unroll
    for (int kk = 0; kk < 2; ++kk)
#pragma unroll
      for (int mt = 0; mt < 4; ++mt)
#pragma unroll
        for (int nt = 0; nt < 2; ++nt)
          s[mt][nt] = __builtin_amdgcn_mfma_f32_16x16x32_bf16(ak[mt][kk], bq[nt][kk], s[mt][nt], 0, 0, 0);
    __builtin_amdgcn_s_setprio(0);

    // issue V^T fragment loads now; latency hides under exp2/P phase
    bf16x8 av[4][2];
#pragma unroll
    for (int mt = 0; mt < 4; ++mt)
#pragma unroll
      for (int kk = 0; kk < 2; ++kk)
        av[mt][kk] = *(const bf16x8*)(tKt + (long)mt * 16 * NTOK + kk * 32);

    // P = exp2(S): no max subtraction; per-lane l accumulation; P -> LDS
#pragma unroll
    for (int mt = 0; mt < 4; ++mt)
#pragma unroll
      for (int nt = 0; nt < 2; ++nt) {
        f32x4 p;
#pragma unroll
        for (int reg = 0; reg < 4; ++reg) p[reg] = __builtin_amdgcn_exp2f(s[mt][nt][reg]);
        lacc[nt] += (p[0] + p[1]) + (p[2] + p[3]);
        // 4 regs = 4 consecutive keys -> packed 8B store, wave-private row
        *(bf16x4*)swz(QP, w * 32 + nt * 16 + l15, mt * 32 + quad * 8) =
            __builtin_convertvector(p, bf16x4);
      }
    // no barrier: each wave reads back only its own 32 qrows of QP

    // O^T += V^T P^T : A from av (global frags), B from QP (P) [qrow][key]
    __builtin_amdgcn_s_setprio(1);
#pragma unroll
    for (int kk = 0; kk < 2; ++kk) {
      bf16x8 bp[2];
#pragma unroll
      for (int nt = 0; nt < 2; ++nt)
        bp[nt] = *(const bf16x8*)swz(QP, w * 32 + nt * 16 + l15, kk * 64 + quad * 16);
#pragma unroll
      for (int mt = 0; mt < 4; ++mt)
#pragma unroll
        for (int nt = 0; nt < 2; ++nt)
          o[mt][nt] = __builtin_amdgcn_mfma_f32_16x16x32_bf16(av[mt][kk], bp[nt], o[mt][nt], 0, 0, 0);
    }
    __builtin_amdgcn_s_setprio(0);
  }

  // epilogue: reduce l across quads, scale, store fp32 out[b,n,h*64+d]
#pragma unroll
  for (int nt = 0; nt < 2; ++nt) {
    float l = lacc[nt];
    l += __shfl_xor(l, 16, 64);
    l += __shfl_xor(l, 32, 64);
    float rl = 1.0f / l;
    int n = q0 + w * 32 + nt * 16 + l15;
#pragma unroll
    for (int mt = 0; mt < 4; ++mt) {
      f32x4 v;
#pragma unroll
      for (int reg = 0; reg < 4; ++reg) v[reg] = o[mt][nt][reg] * rl;
      *(f32x4*)(&out[((long)(b * NTOK + n)) * CDIM + h * HD + mt * 16 + quad * 4]) = v;
    }
  }
}

// ---------------------------------------------------------------------------
extern "C" void kernel_launch(void* const* d_in, const int* in_sizes, int n_in,
                              void* d_out, int out_size, void* d_ws, size_t ws_size,
                              hipStream_t stream) {
  const float* x  = (const float*)d_in[0];
  const float* Wq = (const float*)d_in[1];
  const float* Wk = (const float*)d_in[2];
  // d_in[3] (Wv) intentionally unused — reference bug preserved
  float* out = (float*)d_out;
  char* ws = (char*)d_ws;

  const long NX = (long)2 * NTOK * CDIM;  // 6291456 elems
  const long NW = (long)CDIM * CDIM;      // 589824 elems

  // workspace layout (bytes). Kt aliases xb (xb dead after proj_kernel).
  bf16* xb  = (bf16*)(ws);
  bf16* Ktb = (bf16*)(ws);
  bf16* wqb = (bf16*)(ws + NX * 2);
  bf16* wkb = (bf16*)(ws + NX * 2 + NW * 2);
  bf16* Qb  = (bf16*)(ws + NX * 2 + NW * 4);
  bf16* Kb  = (bf16*)(ws + NX * 2 + NW * 4 + NX * 2);
  // total required: NX*4 + NW*4 + NX*2 = ~40.1 MB

  long tot4 = (NX + 2 * NW) / 4;
  cast_kernel<<<dim3((tot4 + 255) / 256), 256, 0, stream>>>(x, Wq, Wk, xb, wqb, wkb, NX, NW);
  proj_kernel<<<dim3(8192 / 128, CDIM / 128, 2), 256, 0, stream>>>(xb, wqb, wkb, Qb, Kb);
  transpose_kernel<<<dim3(NTOK / 64, 2 * NH), 256, 0, stream>>>(Kb, Ktb);
  attn_kernel<<<dim3(NTOK / 128, 2 * NH), 256, 0, stream>>>(Qb, Kb, Ktb, out);
}

// Round 4
// 228.674 us; speedup vs baseline: 1.9792x; 1.9792x over previous
//
#include <hip/hip_runtime.h>

typedef __bf16 bf16;
typedef __bf16 bf16x4 __attribute__((ext_vector_type(4)));
typedef __bf16 bf16x8 __attribute__((ext_vector_type(8)));
typedef float  f32x4  __attribute__((ext_vector_type(4)));
typedef int    int4v  __attribute__((ext_vector_type(4)));

#define NTOK 4096
#define NH   12
#define HD   64
#define CDIM 768

// C^-0.5 * log2(e), folded into Q at projection time
#define K2SCALE 0.05205928442089389f

#define MFMA __builtin_amdgcn_mfma_f32_16x16x32_bf16

// XOR-swizzled LDS addressing: rows are 64 bf16 = 128 B = 8 x 16B blocks.
// block' = block ^ (row & 7). Verified conflict-free (uniform bank spread)
// for: b128 staging writes, b128 fragment reads, b64 P writes.
__device__ __forceinline__ bf16* swz(bf16* base, int row, int byteoff) {
  return (bf16*)((char*)base + row * 128 +
                 ((((byteoff >> 4) ^ (row & 7)) << 4) | (byteoff & 15)));
}
__device__ __forceinline__ const bf16* swz(const bf16* base, int row, int byteoff) {
  return (const bf16*)((const char*)base + row * 128 +
                 ((((byteoff >> 4) ^ (row & 7)) << 4) | (byteoff & 15)));
}

// ---------------------------------------------------------------------------
// 1) fp32 -> bf16 cast for x, Wq, Wk
// ---------------------------------------------------------------------------
__global__ __launch_bounds__(256) void cast_kernel(
    const float* __restrict__ x, const float* __restrict__ wq, const float* __restrict__ wk,
    bf16* __restrict__ xb, bf16* __restrict__ wqb, bf16* __restrict__ wkb,
    long nx, long nw) {
  long i4 = ((long)blockIdx.x * 256 + threadIdx.x) * 4;
  if (i4 >= nx + 2 * nw) return;
  const float* src; bf16* dst;
  if (i4 < nx)            { src = x  + i4;            dst = xb  + i4; }
  else if (i4 < nx + nw)  { src = wq + (i4 - nx);     dst = wqb + (i4 - nx); }
  else                    { src = wk + (i4 - nx - nw); dst = wkb + (i4 - nx - nw); }
  f32x4 v = *(const f32x4*)src;
  *(bf16x4*)dst = __builtin_convertvector(v, bf16x4);
}

// ---------------------------------------------------------------------------
// 2) projection GEMM (round-0 known-good): y = x @ W^T, tile 128x128, BK=64,
//    reg-prefetch staging, swizzled LDS. blockIdx.z: 0->Q(scaled), 1->K.
//    out layout [B, H, N, 64]
// ---------------------------------------------------------------------------
__global__ __launch_bounds__(256) void proj_kernel(
    const bf16* __restrict__ xb, const bf16* __restrict__ wqb, const bf16* __restrict__ wkb,
    bf16* __restrict__ Qb, bf16* __restrict__ Kb) {
  __shared__ __align__(16) bf16 Ap[128 * 64];
  __shared__ __align__(16) bf16 Bp[128 * 64];
  const int tid = threadIdx.x;
  const int w = tid >> 6, lane = tid & 63, l15 = lane & 15, quad = lane >> 4;
  const int m0 = blockIdx.x * 128;
  const int j0 = blockIdx.y * 128;
  const bf16* W   = blockIdx.z ? wkb : wqb;
  bf16*       Out = blockIdx.z ? Kb  : Qb;
  const float oscale = blockIdx.z ? 1.0f : K2SCALE;

  // per-thread staging geometry: rows (tid>>3)+i*32, 16B chunk (tid&7)
  const int srow = tid >> 3, scb = (tid & 7) * 16, soff = (tid & 7) * 8;
  const bf16* pa = xb + (long)(m0 + srow) * CDIM + soff;
  const bf16* pb = W  + (long)(j0 + srow) * CDIM + soff;

  f32x4 acc[2][8] = {};
  int4v rA[4], rB[4];
#pragma unroll
  for (int i = 0; i < 4; ++i) {
    rA[i] = *(const int4v*)(pa + (long)i * 32 * CDIM);
    rB[i] = *(const int4v*)(pb + (long)i * 32 * CDIM);
  }

  for (int kt = 0; kt < CDIM / 64; ++kt) {
    __syncthreads();  // previous tile's LDS reads done
#pragma unroll
    for (int i = 0; i < 4; ++i) {
      *(int4v*)swz(Ap, srow + i * 32, scb) = rA[i];
      *(int4v*)swz(Bp, srow + i * 32, scb) = rB[i];
    }
    __syncthreads();
    // prefetch next K-slice while computing this one
    const long koff = (long)((kt == CDIM / 64 - 1) ? kt : kt + 1) * 64;
#pragma unroll
    for (int i = 0; i < 4; ++i) {
      rA[i] = *(const int4v*)(pa + (long)i * 32 * CDIM + koff);
      rB[i] = *(const int4v*)(pb + (long)i * 32 * CDIM + koff);
    }
#pragma unroll
    for (int kk = 0; kk < 2; ++kk) {
      bf16x8 a[2], b[8];
#pragma unroll
      for (int rt = 0; rt < 2; ++rt)
        a[rt] = *(const bf16x8*)swz(Ap, w * 32 + rt * 16 + l15, kk * 64 + quad * 16);
#pragma unroll
      for (int ct = 0; ct < 8; ++ct)
        b[ct] = *(const bf16x8*)swz(Bp, ct * 16 + l15, kk * 64 + quad * 16);
#pragma unroll
      for (int rt = 0; rt < 2; ++rt)
#pragma unroll
        for (int ct = 0; ct < 8; ++ct)
          acc[rt][ct] = MFMA(a[rt], b[ct], acc[rt][ct], 0, 0, 0);
    }
  }
#pragma unroll
  for (int rt = 0; rt < 2; ++rt)
#pragma unroll
    for (int ct = 0; ct < 8; ++ct)
#pragma unroll
      for (int reg = 0; reg < 4; ++reg) {
        int m = m0 + w * 32 + rt * 16 + quad * 4 + reg;
        int j = j0 + ct * 16 + l15;
        int b = m >> 12, n = m & (NTOK - 1);
        int h = j >> 6, d = j & (HD - 1);
        Out[(((long)(b * NH + h) * NTOK + n) << 6) + d] = (bf16)(acc[rt][ct][reg] * oscale);
      }
}

// ---------------------------------------------------------------------------
// 3) K [B,H,N,64] -> Kt [B,H,64,N]
// ---------------------------------------------------------------------------
__global__ __launch_bounds__(256) void transpose_kernel(
    const bf16* __restrict__ Kb, bf16* __restrict__ Ktb) {
  __shared__ __align__(16) bf16 T[64 * 72];
  const int tid = threadIdx.x;
  const int n0 = blockIdx.x * 64;
  const long bh = blockIdx.y;
#pragma unroll
  for (int i = 0; i < 2; ++i) {
    int c = tid + i * 256;
    int row = c >> 3, off = (c & 7) * 8;
    bf16x8 v = *(const bf16x8*)(Kb + ((bh << 12) + n0 + row) * HD + off);
#pragma unroll
    for (int e = 0; e < 8; ++e) T[(off + e) * 72 + row] = v[e];
  }
  __syncthreads();
#pragma unroll
  for (int i = 0; i < 2; ++i) {
    int c = tid + i * 256;
    int d = c >> 3, koff = (c & 7) * 8;
    int4v v = *(const int4v*)(&T[d * 72 + koff]);
    *(int4v*)(Ktb + ((bh << 6) + d) * (long)NTOK + n0 + koff) = v;
  }
}

// ---------------------------------------------------------------------------
// 4) flash attention, transposed orientation:
//      S^T = K · Q^T ; P = exp2(S) (no max; scale folded into Q)
//      O^T = V^T · P^T  (V == K, reference bug preserved)
//    Structure: double-buffered Ks/Kts -> ONE barrier per key tile;
//    staging ds_writes for tile t+1 interleaved into tile t's compute;
//    ping-pong prefetch regs (t+2 issued a full iter before its drain);
//    per-mt interleave so exp2/P-writes hide under subsequent MFMAs.
// ---------------------------------------------------------------------------

// QK^T for one 16-key row block MT: 2 swizzled b128 reads + 4 MFMA
#define QKT(SX, MT, KC)                                                        \
  {                                                                            \
    bf16x8 a0 = *(const bf16x8*)swz(KC, (MT) * 16 + l15, quad * 16);           \
    bf16x8 a1 = *(const bf16x8*)swz(KC, (MT) * 16 + l15, 64 + quad * 16);      \
    SX[0] = MFMA(a0, bq[0][0], SX[0], 0, 0, 0);                                \
    SX[1] = MFMA(a0, bq[1][0], SX[1], 0, 0, 0);                                \
    SX[0] = MFMA(a1, bq[0][1], SX[0], 0, 0, 0);                                \
    SX[1] = MFMA(a1, bq[1][1], SX[1], 0, 0, 0);                                \
  }

// exp2 + denominator accumulation + packed P write for row block MT
#define EXP2P(SX, MT)                                                          \
  {                                                                            \
    f32x4 p0, p1;                                                              \
    _Pragma("unroll") for (int r = 0; r < 4; ++r) {                            \
      p0[r] = __builtin_amdgcn_exp2f(SX[0][r]);                                \
      p1[r] = __builtin_amdgcn_exp2f(SX[1][r]);                                \
    }                                                                          \
    lacc[0] += (p0[0] + p0[1]) + (p0[2] + p0[3]);                              \
    lacc[1] += (p1[0] + p1[1]) + (p1[2] + p1[3]);                              \
    *(bf16x4*)swz(QP, w * 32 + l15, (MT) * 32 + quad * 8) =                    \
        __builtin_convertvector(p0, bf16x4);                                   \
    *(bf16x4*)swz(QP, w * 32 + 16 + l15, (MT) * 32 + quad * 8) =               \
        __builtin_convertvector(p1, bf16x4);                                   \
  }

// PV for one 32-key contraction slice KK: 2 bp + 4 av reads, 8 MFMA
#define PVKK(KK, KTC)                                                          \
  {                                                                            \
    bf16x8 bp0 = *(const bf16x8*)swz(QP, w * 32 + l15, (KK) * 64 + quad * 16); \
    bf16x8 bp1 = *(const bf16x8*)swz(QP, w * 32 + 16 + l15, (KK) * 64 + quad * 16); \
    _Pragma("unroll") for (int mt = 0; mt < 4; ++mt) {                         \
      bf16x8 av = *(const bf16x8*)swz(KTC, mt * 16 + l15, (KK) * 64 + quad * 16); \
      o[mt][0] = MFMA(av, bp0, o[mt][0], 0, 0, 0);                             \
      o[mt][1] = MFMA(av, bp1, o[mt][1], 0, 0, 0);                             \
    }                                                                          \
  }

// one key tile: read buf C, stage tile t+1 (regs WK/WT) into buf C^1,
// prefetch tile T2 into regs PK_/PT_, one barrier at the end.
#define HALF_ITER(C, WK, WT, PK_, PT_, T2)                                     \
  {                                                                            \
    const bf16* Kc  = Ks  + (C) * 4096;                                        \
    const bf16* KTc = Kts + (C) * 4096;                                        \
    bf16* KcW  = Ks  + (1 - (C)) * 4096;                                       \
    bf16* KTcW = Kts + (1 - (C)) * 4096;                                       \
    f32x4 s0[2] = {}, s1[2] = {}, s2[2] = {}, s3[2] = {};                      \
    __builtin_amdgcn_s_setprio(1);                                             \
    QKT(s0, 0, Kc)                                                             \
    QKT(s1, 1, Kc)                                                             \
    *(int4v*)swz(KcW, srow, scb) = WK[0];                                      \
    *(int4v*)swz(KcW, srow + 32, scb) = WK[1];                                 \
    EXP2P(s0, 0)                                                               \
    QKT(s2, 2, Kc)                                                             \
    *(int4v*)swz(KTcW, srow, scb) = WT[0];                                     \
    *(int4v*)swz(KTcW, srow + 32, scb) = WT[1];                                \
    EXP2P(s1, 1)                                                               \
    QKT(s3, 3, Kc)                                                             \
    { const long ko = (long)(T2) * 64;                                         \
      PK_[0] = *(const int4v*)(pk + ko * HD);                                  \
      PK_[1] = *(const int4v*)(pk + (ko + 32) * HD);                           \
      PT_[0] = *(const int4v*)(pkt + ko);                                      \
      PT_[1] = *(const int4v*)(pkt + ko + 32L * NTOK); }                       \
    EXP2P(s2, 2)                                                               \
    EXP2P(s3, 3)                                                               \
    PVKK(0, KTc)                                                               \
    PVKK(1, KTc)                                                               \
    __builtin_amdgcn_s_setprio(0);                                             \
    __syncthreads();                                                           \
  }

__global__ __launch_bounds__(256, 3) void attn_kernel(
    const bf16* __restrict__ Qb, const bf16* __restrict__ Kb, const bf16* __restrict__ Ktb,
    float* __restrict__ out) {
  __shared__ __align__(16) bf16 QP[128 * 64];      // Q tile, then P [qrow][key]
  __shared__ __align__(16) bf16 Ks[2 * 64 * 64];   // K  [key][d], double-buffered
  __shared__ __align__(16) bf16 Kts[2 * 64 * 64];  // Kt [d][key], double-buffered

  const int tid = threadIdx.x;
  const int w = tid >> 6, lane = tid & 63, l15 = lane & 15, quad = lane >> 4;
  const int q0 = blockIdx.x * 128;
  const int bh = blockIdx.y;
  const int b = bh / NH, h = bh % NH;
  const bf16* Qhead  = Qb  + (long)bh * NTOK * HD;
  const bf16* Khead  = Kb  + (long)bh * NTOK * HD;
  const bf16* Kthead = Ktb + (long)bh * HD * NTOK;

  // per-thread staging geometry: rows (tid>>3)+{0,32}, 16B chunk (tid&7)
  const int srow = tid >> 3, scb = (tid & 7) * 16, soff = (tid & 7) * 8;
  const bf16* pk  = Khead  + (long)srow * HD + soff;    // tile T: +T*64*HD
  const bf16* pkt = Kthead + (long)srow * NTOK + soff;  // tile T: +T*64

  // stage Q tile (128 x 64)
#pragma unroll
  for (int i = 0; i < 4; ++i) {
    int c = tid + i * 256;
    int row = c >> 3, cb = (c & 7) * 16;
    int4v v = *(const int4v*)(Qhead + (long)(q0 + row) * HD + (c & 7) * 8);
    *(int4v*)swz(QP, row, cb) = v;
  }

  // load tiles 0 (set A) and 1 (set B) into regs; write tile 0 -> buf 0
  int4v rAK[2], rAT[2], rBK[2], rBT[2];
  rAK[0] = *(const int4v*)(pk);
  rAK[1] = *(const int4v*)(pk + 32 * HD);
  rAT[0] = *(const int4v*)(pkt);
  rAT[1] = *(const int4v*)(pkt + 32L * NTOK);
  rBK[0] = *(const int4v*)(pk + 64 * HD);
  rBK[1] = *(const int4v*)(pk + 96 * HD);
  rBT[0] = *(const int4v*)(pkt + 64);
  rBT[1] = *(const int4v*)(pkt + 64 + 32L * NTOK);
  *(int4v*)swz(Ks, srow, scb)       = rAK[0];
  *(int4v*)swz(Ks, srow + 32, scb)  = rAK[1];
  *(int4v*)swz(Kts, srow, scb)      = rAT[0];
  *(int4v*)swz(Kts, srow + 32, scb) = rAT[1];
  __syncthreads();  // Q + tile 0 resident

  // Q^T B-frags: B[k=d][n=qrow], lane l15 = qrow, k = quad*8+j (+32*kk)
  bf16x8 bq[2][2];
#pragma unroll
  for (int nt = 0; nt < 2; ++nt)
#pragma unroll
    for (int kk = 0; kk < 2; ++kk)
      bq[nt][kk] = *(const bf16x8*)swz(QP, w * 32 + nt * 16 + l15, kk * 64 + quad * 16);
  // From here on, QP rows [w*32, w*32+32) are wave-private P space.

  f32x4 o[4][2] = {};          // O^T: mt over d (4), nt over qrow (2)
  float lacc[2] = {0.f, 0.f};  // per-lane partial softmax denominators

  // iter t: read buf t&1; write tile t+1 from set[(t+1)&1]; prefetch t+2
  // into set[t&1]. Prologue: A=tile0 (already written), B=tile1.
  for (int t = 0; t < NTOK / 64; t += 2) {
    const int n2a = (t + 2 < NTOK / 64) ? t + 2 : NTOK / 64 - 1;
    const int n2b = (t + 3 < NTOK / 64) ? t + 3 : NTOK / 64 - 1;
    HALF_ITER(0, rBK, rBT, rAK, rAT, n2a)
    HALF_ITER(1, rAK, rAT, rBK, rBT, n2b)
  }

  // epilogue: reduce l across quads, scale, store fp32 out[b,n,h*64+d]
#pragma unroll
  for (int nt = 0; nt < 2; ++nt) {
    float l = lacc[nt];
    l += __shfl_xor(l, 16, 64);
    l += __shfl_xor(l, 32, 64);
    float rl = 1.0f / l;
    int n = q0 + w * 32 + nt * 16 + l15;
#pragma unroll
    for (int mt = 0; mt < 4; ++mt) {
      f32x4 v;
#pragma unroll
      for (int reg = 0; reg < 4; ++reg) v[reg] = o[mt][nt][reg] * rl;
      *(f32x4*)(&out[((long)(b * NTOK + n)) * CDIM + h * HD + mt * 16 + quad * 4]) = v;
    }
  }
}

// ---------------------------------------------------------------------------
extern "C" void kernel_launch(void* const* d_in, const int* in_sizes, int n_in,
                              void* d_out, int out_size, void* d_ws, size_t ws_size,
                              hipStream_t stream) {
  const float* x  = (const float*)d_in[0];
  const float* Wq = (const float*)d_in[1];
  const float* Wk = (const float*)d_in[2];
  // d_in[3] (Wv) intentionally unused — reference bug preserved
  float* out = (float*)d_out;
  char* ws = (char*)d_ws;

  const long NX = (long)2 * NTOK * CDIM;  // 6291456 elems
  const long NW = (long)CDIM * CDIM;      // 589824 elems

  // workspace layout (bytes). Kt aliases xb (xb dead after proj_kernel).
  bf16* xb  = (bf16*)(ws);
  bf16* Ktb = (bf16*)(ws);
  bf16* wqb = (bf16*)(ws + NX * 2);
  bf16* wkb = (bf16*)(ws + NX * 2 + NW * 2);
  bf16* Qb  = (bf16*)(ws + NX * 2 + NW * 4);
  bf16* Kb  = (bf16*)(ws + NX * 2 + NW * 4 + NX * 2);
  // total required: NX*4 + NW*4 + NX*2 = ~40.1 MB

  long tot4 = (NX + 2 * NW) / 4;
  cast_kernel<<<dim3((tot4 + 255) / 256), 256, 0, stream>>>(x, Wq, Wk, xb, wqb, wkb, NX, NW);
  proj_kernel<<<dim3(8192 / 128, CDIM / 128, 2), 256, 0, stream>>>(xb, wqb, wkb, Qb, Kb);
  transpose_kernel<<<dim3(NTOK / 64, 2 * NH), 256, 0, stream>>>(Kb, Ktb);
  attn_kernel<<<dim3(NTOK / 128, 2 * NH), 256, 0, stream>>>(Qb, Kb, Ktb, out);
}